// Round 2
// baseline (1592.651 us; speedup 1.0000x reference)
//
#include <hip/hip_runtime.h>
#include <math.h>

#define T_ 128
#define NE_ 64
#define NA_ 8
#define B_ 512
#define OBS_ 64
#define D_ 128
#define CH_ 128
#define VH_ 256
#define M_ (T_*B_)   // 65536
#define TC_ 32       // GRU time-chunk
#define MC_ (TC_*B_) // 16384 rows per chunk

__device__ __forceinline__ float sigmoidf_(float x){ return 1.f/(1.f+__expf(-x)); }

// ---------------------------------------------------------------------------
// Generic fp32 tiled GEMM: C[M,N] = epi(A[M,K] @ B[K,N] + bias)
// BM=128, BN=64, BK=16, 256 threads, 8x4 per-thread tile.
// DUAL: A is [A1 | A2] concatenated along K at K1 (both row-major)
// ACT==1: relu.  RESID: += resid[m][n] AFTER act.  SCALE: *= (dones[m]?0:1) last.
// ---------------------------------------------------------------------------
template<int ACT, bool DUAL, bool RESID, bool SCALE>
__global__ __launch_bounds__(256)
void gemm_k(const float* __restrict__ A, const float* __restrict__ A2,
            const float* __restrict__ Bm, const float* __restrict__ bias,
            const float* __restrict__ resid, const int* __restrict__ dones,
            float* __restrict__ C, int M, int N, int K, int K1)
{
  constexpr int BM=128, BN=64, BK=16;
  __shared__ float As[BK][BM+4];
  __shared__ float Bs[BK][BN];
  const int tid = threadIdx.x;
  const int n0 = blockIdx.x * BN;
  const int m0 = blockIdx.y * BM;
  const int tn = tid & 15, tm = tid >> 4;

  float acc[8][4];
  #pragma unroll
  for (int r=0;r<8;r++)
    #pragma unroll
    for (int j=0;j<4;j++) acc[r][j]=0.f;

  for (int k0=0; k0<K; k0+=BK) {
    const float* Ab; int As_stride; int kk;
    if (DUAL && k0 >= K1) { Ab = A2; kk = k0 - K1; As_stride = K - K1; }
    else                  { Ab = A;  kk = k0;      As_stride = DUAL ? K1 : K; }
    #pragma unroll
    for (int i=0;i<2;i++){
      int f = tid + i*256;           // 512 float4 = 128 rows x 16 k
      int m = f >> 2, kq = (f & 3)*4;
      float4 v = *(const float4*)&Ab[(size_t)(m0+m)*As_stride + kk + kq];
      As[kq+0][m]=v.x; As[kq+1][m]=v.y; As[kq+2][m]=v.z; As[kq+3][m]=v.w;
    }
    {
      int f = tid;                   // 256 float4 = 16 k x 64 n
      int k = f >> 4, nq = (f & 15)*4;
      *(float4*)&Bs[k][nq] = *(const float4*)&Bm[(size_t)(k0+k)*N + n0 + nq];
    }
    __syncthreads();
    #pragma unroll
    for (int k=0;k<BK;k++){
      float4 b4 = *(float4*)&Bs[k][tn*4];
      float4 a0 = *(float4*)&As[k][tm*8];
      float4 a1 = *(float4*)&As[k][tm*8+4];
      float av[8] = {a0.x,a0.y,a0.z,a0.w,a1.x,a1.y,a1.z,a1.w};
      float bv[4] = {b4.x,b4.y,b4.z,b4.w};
      #pragma unroll
      for (int r=0;r<8;r++)
        #pragma unroll
        for (int j=0;j<4;j++) acc[r][j] = fmaf(av[r], bv[j], acc[r][j]);
    }
    __syncthreads();
  }

  float4 bias4 = make_float4(0.f,0.f,0.f,0.f);
  if (bias) bias4 = *(const float4*)&bias[n0 + tn*4];
  #pragma unroll
  for (int r=0;r<8;r++){
    int m = m0 + tm*8 + r;
    float4 c;
    c.x = acc[r][0]+bias4.x; c.y = acc[r][1]+bias4.y;
    c.z = acc[r][2]+bias4.z; c.w = acc[r][3]+bias4.w;
    if (ACT==1){ c.x=fmaxf(c.x,0.f); c.y=fmaxf(c.y,0.f); c.z=fmaxf(c.z,0.f); c.w=fmaxf(c.w,0.f); }
    if (RESID){
      float4 rv = *(const float4*)&resid[(size_t)m*N + n0 + tn*4];
      c.x+=rv.x; c.y+=rv.y; c.z+=rv.z; c.w+=rv.w;
    }
    if (SCALE){
      float al = (dones[m]!=0) ? 0.f : 1.f;
      c.x*=al; c.y*=al; c.z*=al; c.w*=al;
    }
    *(float4*)&C[(size_t)m*N + n0 + tn*4] = c;
  }
}

// ---------------------------------------------------------------------------
// GRU scan over a time chunk [t0, t0+tc). 128 blocks x 128 threads, 4 rows/blk.
// h carried in/out of global between chunks; reset-at-consumption semantics:
// chunk start applies dones[t0]; within chunk applies dones[t0+lt+1]; the
// boundary reset is applied by the NEXT chunk's init (idempotent & exact).
// e_out[t] = h_new * alive[t]; hout gets the UNRESET final h of the chunk.
// ---------------------------------------------------------------------------
__global__ __launch_bounds__(128)
void gru_k(const float* __restrict__ gi, const float* __restrict__ hin,
           const int* __restrict__ dones, const float* __restrict__ Wh,
           const float* __restrict__ bhn, float* __restrict__ e_out,
           float* __restrict__ hout, int t0, int tc)
{
  __shared__ float hs[4][D_];
  __shared__ float dn[TC_][4];
  __shared__ float bhns[D_];
  const int bid = blockIdx.x;     // 0..127
  const int r0  = bid*4;
  const int c   = threadIdx.x;    // 0..127

  for (int f = c; f < tc*4; f += 128){
    int t = f >> 2, r = f & 3;
    dn[t][r] = (dones[(size_t)(t0+t)*B_ + r0 + r] != 0) ? 1.f : 0.f;
  }
  bhns[c] = bhn[c];
  #pragma unroll
  for (int r=0;r<4;r++) hs[r][c] = hin[(size_t)(r0+r)*D_ + c];
  __syncthreads();
  #pragma unroll
  for (int r=0;r<4;r++) if (dn[0][r] > 0.5f) hs[r][c] = 0.f;
  __syncthreads();

  for (int lt=0; lt<tc; lt++){
    const int gt = t0 + lt;
    float grv[4], gzv[4], gnv[4];
    #pragma unroll
    for (int r=0;r<4;r++){
      const float* gp = &gi[((size_t)lt*B_ + r0 + r)*384];
      grv[r]=gp[c]; gzv[r]=gp[c+128]; gnv[r]=gp[c+256];
    }
    float aR[4]={0,0,0,0}, aZ[4]={0,0,0,0}, aN[4]={0,0,0,0};
    for (int k4=0; k4<D_; k4+=4){
      float h4[4][4];
      #pragma unroll
      for (int r=0;r<4;r++) *(float4*)h4[r] = *(const float4*)&hs[r][k4];
      const float* wp = &Wh[(size_t)k4*384 + c];
      #pragma unroll
      for (int kk=0;kk<4;kk++){
        float wr = wp[kk*384];
        float wz = wp[kk*384+128];
        float wn = wp[kk*384+256];
        #pragma unroll
        for (int r=0;r<4;r++){
          aR[r] = fmaf(h4[r][kk], wr, aR[r]);
          aZ[r] = fmaf(h4[r][kk], wz, aZ[r]);
          aN[r] = fmaf(h4[r][kk], wn, aN[r]);
        }
      }
    }
    float hnew[4];
    #pragma unroll
    for (int r=0;r<4;r++){
      float rg = sigmoidf_(grv[r] + aR[r]);
      float zg = sigmoidf_(gzv[r] + aZ[r]);
      float ng = tanhf(gnv[r] + rg*(aN[r] + bhns[c]));
      float hold = hs[r][c];
      hnew[r] = (1.f - zg)*ng + zg*hold;
      e_out[((size_t)gt*B_ + r0 + r)*D_ + c] = hnew[r] * (1.f - dn[lt][r]);
    }
    __syncthreads();
    #pragma unroll
    for (int r=0;r<4;r++){
      float hv = hnew[r];
      if (lt+1 < tc && dn[lt+1][r] > 0.5f) hv = 0.f;
      hs[r][c] = hv;
    }
    __syncthreads();
  }
  #pragma unroll
  for (int r=0;r<4;r++) hout[(size_t)(r0+r)*D_ + c] = hs[r][c];
}

// ---------------------------------------------------------------------------
// Coupling: per (t, env) block. acat[m][0:128]=a_i, [128:256]=a_j.
// C_ij = sigmoid(sum_h relu(ai[i]+aj[j]+cb)*w + cob), C_ii = 0.
// ctx[i] = sum_j C_ij * e[j].  (alive_j mask redundant: e_j already zeroed)
// ---------------------------------------------------------------------------
__global__ __launch_bounds__(256)
void couple_k(const float* __restrict__ acat, const float* __restrict__ e,
              const float* __restrict__ chb, const float* __restrict__ cow,
              const float* __restrict__ cob, float* __restrict__ ctx)
{
  __shared__ float ai[NA_][CH_], aj[NA_][CH_], es[NA_][D_], cbw[CH_], cww[CH_], Cs[NA_][NA_];
  const int m0 = blockIdx.x * NA_;       // t*512 + env*8
  const int tid = threadIdx.x;

  for (int f = tid; f < 512; f += 256) { // 8 rows x 64 float4 of acat
    int j = f >> 6, q = (f & 63)*4;
    float4 v = *(const float4*)&acat[(size_t)(m0+j)*256 + q];
    if (q < 128) *(float4*)&ai[j][q]     = v;
    else         *(float4*)&aj[j][q-128] = v;
  }
  {
    int f = tid;                         // 8 rows x 32 float4 of e
    int j = f >> 5, q = (f & 31)*4;
    *(float4*)&es[j][q] = *(const float4*)&e[(size_t)(m0+j)*D_ + q];
  }
  if (tid < 128) { cbw[tid] = chb[tid]; cww[tid] = cow[tid]; }
  __syncthreads();

  {
    int p = tid >> 2, q = tid & 3;       // 64 pairs x 4 partial threads
    int i = p >> 3, j = p & 7;
    float s = 0.f;
    #pragma unroll
    for (int h = 0; h < 32; h++){
      int hh = q*32 + h;
      s += fmaxf(ai[i][hh] + aj[j][hh] + cbw[hh], 0.f) * cww[hh];
    }
    s += __shfl_down(s, 2);
    s += __shfl_down(s, 1);
    if (q == 0) {
      float Cv = sigmoidf_(s + cob[0]);
      Cs[i][j] = (i==j) ? 0.f : Cv;
    }
  }
  __syncthreads();
  #pragma unroll
  for (int rep=0; rep<4; rep++){
    int idx = rep*256 + tid;
    int i = idx >> 7, d = idx & 127;
    float s = 0.f;
    #pragma unroll
    for (int j=0;j<NA_;j++) s = fmaf(Cs[i][j], es[j][d], s);
    ctx[(size_t)(m0+i)*D_ + d] = s;
  }
}

// pack Bcat[k][n] = (n<128) ? couple_h_w[k][n] : couple_h_w[128+k][n-128]
__global__ __launch_bounds__(256)
void pack_k(const float* __restrict__ chw, float* __restrict__ bcat)
{
  int idx = blockIdx.x*256 + threadIdx.x;   // < 32768
  int k = idx >> 8, n = idx & 255;
  bcat[idx] = (n < 128) ? chw[k*128 + n] : chw[(128+k)*128 + (n-128)];
}

// values[m] = v2[m] . w + b   (one wave per row)
__global__ __launch_bounds__(256)
void vout_k(const float* __restrict__ v2, const float* __restrict__ w,
            const float* __restrict__ b, float* __restrict__ values)
{
  int row  = blockIdx.x*4 + (threadIdx.x >> 6);
  int lane = threadIdx.x & 63;
  const float* vr = &v2[(size_t)row*VH_];
  float s = 0.f;
  #pragma unroll
  for (int i=0;i<4;i++) s = fmaf(vr[lane + 64*i], w[lane + 64*i], s);
  #pragma unroll
  for (int off=32; off; off>>=1) s += __shfl_down(s, off);
  if (lane==0) values[row] = s + b[0];
}

extern "C" void kernel_launch(void* const* d_in, const int* in_sizes, int n_in,
                              void* d_out, int out_size, void* d_ws, size_t ws_size,
                              hipStream_t stream) {
  const float* hidden = (const float*)d_in[0];
  const float* obs    = (const float*)d_in[1];
  const int*   dones  = (const int*)  d_in[2];
  const float* e1w = (const float*)d_in[3];
  const float* e1b = (const float*)d_in[4];
  const float* e2w = (const float*)d_in[5];
  const float* e2b = (const float*)d_in[6];
  const float* gWi = (const float*)d_in[7];
  const float* gbi = (const float*)d_in[8];
  const float* gWh = (const float*)d_in[9];
  const float* gbhn= (const float*)d_in[10];
  const float* chw = (const float*)d_in[11];
  const float* chb = (const float*)d_in[12];
  const float* cow = (const float*)d_in[13];
  const float* cob = (const float*)d_in[14];
  const float* uhw = (const float*)d_in[15];
  const float* uhb = (const float*)d_in[16];
  const float* uow = (const float*)d_in[17];
  const float* uob = (const float*)d_in[18];
  const float* v1w = (const float*)d_in[19];
  const float* v1b = (const float*)d_in[20];
  const float* v2w = (const float*)d_in[21];
  const float* v2b = (const float*)d_in[22];
  const float* vow = (const float*)d_in[23];
  const float* vob = (const float*)d_in[24];
  (void)in_sizes; (void)n_in; (void)out_size;

  float* out_hidden = (float*)d_out;
  float* out_values = (float*)d_out + (size_t)B_*D_;

  // Pools (float offsets). Peak 42,041,344 floats = 160.4 MB (< 256 MiB ws).
  float* ws   = (float*)d_ws;
  float* P0   = ws;                  //  8,388,608  emb1 / ctx   (32MB)
  float* P1   = ws + 8388608;        //  8,388,608  emb2 / dpre  (32MB)
  float* P2   = ws + 16777216;       //  8,388,608  e            (32MB)
  float* P3   = ws + 25165824;       // 16,777,216  gi-chunk / acat / v1 (64MB)
  float* Hc   = ws + 41943040;       //     65,536  GRU hidden carry
  float* bcat = ws + 42008576;       //     32,768  packed [W1|W2]
  float* v2   = ws;                  // 16,777,216  v2 overlays P0+P1 (dead then)
  if (ws_size < (size_t)42041344 * sizeof(float)) return;

  dim3 blk(256);
  // embed1: relu(obs @ e1w + e1b)  M=65536 K=64 N=128
  gemm_k<1,false,false,false><<<dim3(2,512), blk, 0, stream>>>(obs,nullptr,e1w,e1b,nullptr,nullptr,P0,M_,128,64,0);
  // embed2: relu(emb1 @ e2w + e2b) K=128 N=128
  gemm_k<1,false,false,false><<<dim3(2,512), blk, 0, stream>>>(P0,nullptr,e2w,e2b,nullptr,nullptr,P1,M_,128,128,0);

  // GRU in 4 time-chunks: gi for chunk -> P3, then scan chunk.
  for (int c4=0; c4<4; c4++){
    const float* emb2c = P1 + (size_t)c4*MC_*D_;
    gemm_k<0,false,false,false><<<dim3(6,128), blk, 0, stream>>>(emb2c,nullptr,gWi,gbi,nullptr,nullptr,P3,MC_,384,128,0);
    const float* hin = (c4==0) ? hidden : Hc;
    float* hout = (c4==3) ? out_hidden : Hc;
    gru_k<<<dim3(128), dim3(128), 0, stream>>>(P3,hin,dones,gWh,gbhn,P2,hout,c4*TC_,TC_);
  }

  // pack [W1|W2] for coupling
  pack_k<<<dim3(128), blk, 0, stream>>>(chw, bcat);

  for (int it=0; it<2; it++){
    // acat = e @ [W1|W2]  N=256
    gemm_k<0,false,false,false><<<dim3(4,512), blk, 0, stream>>>(P2,nullptr,bcat,nullptr,nullptr,nullptr,P3,M_,256,128,0);
    // coupling + context -> P0
    couple_k<<<dim3(T_*NE_), blk, 0, stream>>>(P3, P2, chb, cow, cob, P0);
    // dpre = relu(e@U1 + ctx@U2 + uhb)   dual-A K=256, split 128 -> P1
    gemm_k<1,true,false,false><<<dim3(2,512), blk, 0, stream>>>(P2,P0,uhw,uhb,nullptr,nullptr,P1,M_,128,256,128);
    // e = (e + relu(dpre@uow + uob)) * alive   (in place on P2)
    gemm_k<1,false,true,true><<<dim3(2,512), blk, 0, stream>>>(P1,nullptr,uow,uob,P2,dones,P2,M_,128,128,0);
  }
  // value head: v1 -> P3, v2 -> [P0;P1], values -> out
  gemm_k<1,false,false,false><<<dim3(4,512), blk, 0, stream>>>(P2,nullptr,v1w,v1b,nullptr,nullptr,P3,M_,256,128,0);
  gemm_k<1,false,false,false><<<dim3(4,512), blk, 0, stream>>>(P3,nullptr,v2w,v2b,nullptr,nullptr,v2,M_,256,256,0);
  vout_k<<<dim3(M_/4), blk, 0, stream>>>(v2, vow, vob, out_values);
}

// Round 3
// 1123.964 us; speedup vs baseline: 1.4170x; 1.4170x over previous
//
#include <hip/hip_runtime.h>
#include <math.h>

#define T_ 128
#define NE_ 64
#define NA_ 8
#define B_ 512
#define OBS_ 64
#define D_ 128
#define CH_ 128
#define VH_ 256
#define M_ (T_*B_)   // 65536
#define TC_ 32       // GRU time-chunk
#define MC_ (TC_*B_) // 16384 rows per chunk

__device__ __forceinline__ float sigmoidf_(float x){ return 1.f/(1.f+__expf(-x)); }

// ---------------------------------------------------------------------------
// Generic fp32 tiled GEMM: C[M,N] = epi(A[M,K] @ B[K,N] + bias)
// BM=128, BN=64, BK=16, 256 threads, 8x4 per-thread tile.
// DUAL: A is [A1 | A2] concatenated along K at K1 (both row-major)
// ACT==1: relu.  RESID: += resid[m][n] AFTER act.  SCALE: *= (dones[m]?0:1) last.
// ---------------------------------------------------------------------------
template<int ACT, bool DUAL, bool RESID, bool SCALE>
__global__ __launch_bounds__(256)
void gemm_k(const float* __restrict__ A, const float* __restrict__ A2,
            const float* __restrict__ Bm, const float* __restrict__ bias,
            const float* __restrict__ resid, const int* __restrict__ dones,
            float* __restrict__ C, int M, int N, int K, int K1)
{
  constexpr int BM=128, BN=64, BK=16;
  __shared__ float As[BK][BM+4];
  __shared__ float Bs[BK][BN];
  const int tid = threadIdx.x;
  const int n0 = blockIdx.x * BN;
  const int m0 = blockIdx.y * BM;
  const int tn = tid & 15, tm = tid >> 4;

  float acc[8][4];
  #pragma unroll
  for (int r=0;r<8;r++)
    #pragma unroll
    for (int j=0;j<4;j++) acc[r][j]=0.f;

  for (int k0=0; k0<K; k0+=BK) {
    const float* Ab; int As_stride; int kk;
    if (DUAL && k0 >= K1) { Ab = A2; kk = k0 - K1; As_stride = K - K1; }
    else                  { Ab = A;  kk = k0;      As_stride = DUAL ? K1 : K; }
    #pragma unroll
    for (int i=0;i<2;i++){
      int f = tid + i*256;           // 512 float4 = 128 rows x 16 k
      int m = f >> 2, kq = (f & 3)*4;
      float4 v = *(const float4*)&Ab[(size_t)(m0+m)*As_stride + kk + kq];
      As[kq+0][m]=v.x; As[kq+1][m]=v.y; As[kq+2][m]=v.z; As[kq+3][m]=v.w;
    }
    {
      int f = tid;                   // 256 float4 = 16 k x 64 n
      int k = f >> 4, nq = (f & 15)*4;
      *(float4*)&Bs[k][nq] = *(const float4*)&Bm[(size_t)(k0+k)*N + n0 + nq];
    }
    __syncthreads();
    #pragma unroll
    for (int k=0;k<BK;k++){
      float4 b4 = *(float4*)&Bs[k][tn*4];
      float4 a0 = *(float4*)&As[k][tm*8];
      float4 a1 = *(float4*)&As[k][tm*8+4];
      float av[8] = {a0.x,a0.y,a0.z,a0.w,a1.x,a1.y,a1.z,a1.w};
      float bv[4] = {b4.x,b4.y,b4.z,b4.w};
      #pragma unroll
      for (int r=0;r<8;r++)
        #pragma unroll
        for (int j=0;j<4;j++) acc[r][j] = fmaf(av[r], bv[j], acc[r][j]);
    }
    __syncthreads();
  }

  float4 bias4 = make_float4(0.f,0.f,0.f,0.f);
  if (bias) bias4 = *(const float4*)&bias[n0 + tn*4];
  #pragma unroll
  for (int r=0;r<8;r++){
    int m = m0 + tm*8 + r;
    float4 c;
    c.x = acc[r][0]+bias4.x; c.y = acc[r][1]+bias4.y;
    c.z = acc[r][2]+bias4.z; c.w = acc[r][3]+bias4.w;
    if (ACT==1){ c.x=fmaxf(c.x,0.f); c.y=fmaxf(c.y,0.f); c.z=fmaxf(c.z,0.f); c.w=fmaxf(c.w,0.f); }
    if (RESID){
      float4 rv = *(const float4*)&resid[(size_t)m*N + n0 + tn*4];
      c.x+=rv.x; c.y+=rv.y; c.z+=rv.z; c.w+=rv.w;
    }
    if (SCALE){
      float al = (dones[m]!=0) ? 0.f : 1.f;
      c.x*=al; c.y*=al; c.z*=al; c.w*=al;
    }
    *(float4*)&C[(size_t)m*N + n0 + tn*4] = c;
  }
}

// ---------------------------------------------------------------------------
// GRU scan, weights-in-registers. One block per batch row (512 blocks),
// 384 threads: thread c owns gate-column c; its 128 Wh weights live in VGPRs
// for the whole chunk (Wh is time-invariant). Per step: h broadcast from LDS,
// 128 FMA/thread, 3KB LDS gate-exchange, combine on threads c<128.
// Chunked over T (boundary reset applied by next chunk's init; exact).
// ---------------------------------------------------------------------------
__global__ __launch_bounds__(384)
void gru2_k(const float* __restrict__ gi, const float* __restrict__ hin,
            const int* __restrict__ dones, const float* __restrict__ Wh,
            const float* __restrict__ bhn, float* __restrict__ e_out,
            float* __restrict__ hout, int t0, int tc)
{
  __shared__ float hs[D_];
  __shared__ float hsum[384];
  __shared__ float gis[384];
  __shared__ float dn[TC_];
  __shared__ float bhns[D_];
  const int row = blockIdx.x;     // 0..511
  const int c   = threadIdx.x;    // 0..383

  // one-time: weights for column c into registers (coalesced across c)
  float w[D_];
  #pragma unroll
  for (int k=0;k<D_;k++) w[k] = Wh[(size_t)k*384 + c];

  for (int f=c; f<tc; f+=384)
    dn[f] = (dones[(size_t)(t0+f)*B_ + row] != 0) ? 1.f : 0.f;
  if (c < D_) { bhns[c] = bhn[c]; hs[c] = hin[(size_t)row*D_ + c]; }
  __syncthreads();
  if (c < D_ && dn[0] > 0.5f) hs[c] = 0.f;
  float gcur = gi[(size_t)row*384 + c];
  __syncthreads();

  for (int lt=0; lt<tc; lt++){
    float gn = 0.f;
    if (lt+1 < tc) gn = gi[((size_t)(lt+1)*B_ + row)*384 + c];
    float acc = 0.f;
    #pragma unroll
    for (int k4=0;k4<D_;k4+=4){
      float4 h4 = *(const float4*)&hs[k4];
      acc = fmaf(h4.x, w[k4+0], acc);
      acc = fmaf(h4.y, w[k4+1], acc);
      acc = fmaf(h4.z, w[k4+2], acc);
      acc = fmaf(h4.w, w[k4+3], acc);
    }
    hsum[c] = acc;
    gis[c]  = gcur;
    __syncthreads();
    if (c < D_){
      float rg = sigmoidf_(gis[c]     + hsum[c]);
      float zg = sigmoidf_(gis[c+128] + hsum[c+128]);
      float ng = tanhf(gis[c+256] + rg*(hsum[c+256] + bhns[c]));
      float hold = hs[c];
      float hnew = (1.f - zg)*ng + zg*hold;
      e_out[((size_t)(t0+lt)*B_ + row)*D_ + c] = hnew * (1.f - dn[lt]);
      float hv = hnew;
      if (lt+1 < tc && dn[lt+1] > 0.5f) hv = 0.f;
      hs[c] = hv;
    }
    __syncthreads();
    gcur = gn;
  }
  if (c < D_) hout[(size_t)row*D_ + c] = hs[c];
}

// ---------------------------------------------------------------------------
// Coupling: per (t, env) block. acat[m][0:128]=a_i, [128:256]=a_j.
// C_ij = sigmoid(sum_h relu(ai[i]+aj[j]+cb)*w + cob), C_ii = 0.
// ctx[i] = sum_j C_ij * e[j].
// ---------------------------------------------------------------------------
__global__ __launch_bounds__(256)
void couple_k(const float* __restrict__ acat, const float* __restrict__ e,
              const float* __restrict__ chb, const float* __restrict__ cow,
              const float* __restrict__ cob, float* __restrict__ ctx)
{
  __shared__ float ai[NA_][CH_], aj[NA_][CH_], es[NA_][D_], cbw[CH_], cww[CH_], Cs[NA_][NA_];
  const int m0 = blockIdx.x * NA_;       // t*512 + env*8
  const int tid = threadIdx.x;

  for (int f = tid; f < 512; f += 256) { // 8 rows x 64 float4 of acat
    int j = f >> 6, q = (f & 63)*4;
    float4 v = *(const float4*)&acat[(size_t)(m0+j)*256 + q];
    if (q < 128) *(float4*)&ai[j][q]     = v;
    else         *(float4*)&aj[j][q-128] = v;
  }
  {
    int f = tid;                         // 8 rows x 32 float4 of e
    int j = f >> 5, q = (f & 31)*4;
    *(float4*)&es[j][q] = *(const float4*)&e[(size_t)(m0+j)*D_ + q];
  }
  if (tid < 128) { cbw[tid] = chb[tid]; cww[tid] = cow[tid]; }
  __syncthreads();

  {
    int p = tid >> 2, q = tid & 3;       // 64 pairs x 4 partial threads
    int i = p >> 3, j = p & 7;
    float s = 0.f;
    #pragma unroll
    for (int h = 0; h < 32; h++){
      int hh = q*32 + h;
      s += fmaxf(ai[i][hh] + aj[j][hh] + cbw[hh], 0.f) * cww[hh];
    }
    s += __shfl_down(s, 2);
    s += __shfl_down(s, 1);
    if (q == 0) {
      float Cv = sigmoidf_(s + cob[0]);
      Cs[i][j] = (i==j) ? 0.f : Cv;
    }
  }
  __syncthreads();
  #pragma unroll
  for (int rep=0; rep<4; rep++){
    int idx = rep*256 + tid;
    int i = idx >> 7, d = idx & 127;
    float s = 0.f;
    #pragma unroll
    for (int j=0;j<NA_;j++) s = fmaf(Cs[i][j], es[j][d], s);
    ctx[(size_t)(m0+i)*D_ + d] = s;
  }
}

// pack Bcat[k][n] = (n<128) ? couple_h_w[k][n] : couple_h_w[128+k][n-128]
__global__ __launch_bounds__(256)
void pack_k(const float* __restrict__ chw, float* __restrict__ bcat)
{
  int idx = blockIdx.x*256 + threadIdx.x;   // < 32768
  int k = idx >> 8, n = idx & 255;
  bcat[idx] = (n < 128) ? chw[k*128 + n] : chw[(128+k)*128 + (n-128)];
}

// values[m] = v2[m] . w + b   (one wave per row)
__global__ __launch_bounds__(256)
void vout_k(const float* __restrict__ v2, const float* __restrict__ w,
            const float* __restrict__ b, float* __restrict__ values)
{
  int row  = blockIdx.x*4 + (threadIdx.x >> 6);
  int lane = threadIdx.x & 63;
  const float* vr = &v2[(size_t)row*VH_];
  float s = 0.f;
  #pragma unroll
  for (int i=0;i<4;i++) s = fmaf(vr[lane + 64*i], w[lane + 64*i], s);
  #pragma unroll
  for (int off=32; off; off>>=1) s += __shfl_down(s, off);
  if (lane==0) values[row] = s + b[0];
}

extern "C" void kernel_launch(void* const* d_in, const int* in_sizes, int n_in,
                              void* d_out, int out_size, void* d_ws, size_t ws_size,
                              hipStream_t stream) {
  const float* hidden = (const float*)d_in[0];
  const float* obs    = (const float*)d_in[1];
  const int*   dones  = (const int*)  d_in[2];
  const float* e1w = (const float*)d_in[3];
  const float* e1b = (const float*)d_in[4];
  const float* e2w = (const float*)d_in[5];
  const float* e2b = (const float*)d_in[6];
  const float* gWi = (const float*)d_in[7];
  const float* gbi = (const float*)d_in[8];
  const float* gWh = (const float*)d_in[9];
  const float* gbhn= (const float*)d_in[10];
  const float* chw = (const float*)d_in[11];
  const float* chb = (const float*)d_in[12];
  const float* cow = (const float*)d_in[13];
  const float* cob = (const float*)d_in[14];
  const float* uhw = (const float*)d_in[15];
  const float* uhb = (const float*)d_in[16];
  const float* uow = (const float*)d_in[17];
  const float* uob = (const float*)d_in[18];
  const float* v1w = (const float*)d_in[19];
  const float* v1b = (const float*)d_in[20];
  const float* v2w = (const float*)d_in[21];
  const float* v2b = (const float*)d_in[22];
  const float* vow = (const float*)d_in[23];
  const float* vob = (const float*)d_in[24];
  (void)in_sizes; (void)n_in; (void)out_size;

  float* out_hidden = (float*)d_out;
  float* out_values = (float*)d_out + (size_t)B_*D_;

  // Pools (float offsets). Peak 42,041,344 floats = 160.4 MB (known to fit).
  float* ws   = (float*)d_ws;
  float* P0   = ws;                  //  8,388,608  emb1 / ctx   (32MB)
  float* P1   = ws + 8388608;        //  8,388,608  emb2 / dpre  (32MB)
  float* P2   = ws + 16777216;       //  8,388,608  e            (32MB)
  float* P3   = ws + 25165824;       // 16,777,216  gi-chunk / acat / v1 (64MB)
  float* Hc   = ws + 41943040;       //     65,536  GRU hidden carry
  float* bcat = ws + 42008576;       //     32,768  packed [W1|W2]
  float* v2   = ws;                  // 16,777,216  v2 overlays P0+P1 (dead then)
  if (ws_size < (size_t)42041344 * sizeof(float)) return;

  dim3 blk(256);
  // embed1: relu(obs @ e1w + e1b)  M=65536 K=64 N=128
  gemm_k<1,false,false,false><<<dim3(2,512), blk, 0, stream>>>(obs,nullptr,e1w,e1b,nullptr,nullptr,P0,M_,128,64,0);
  // embed2: relu(emb1 @ e2w + e2b) K=128 N=128
  gemm_k<1,false,false,false><<<dim3(2,512), blk, 0, stream>>>(P0,nullptr,e2w,e2b,nullptr,nullptr,P1,M_,128,128,0);

  // GRU in 4 time-chunks: gi for chunk -> P3, then scan chunk.
  for (int c4=0; c4<4; c4++){
    const float* emb2c = P1 + (size_t)c4*MC_*D_;
    gemm_k<0,false,false,false><<<dim3(6,128), blk, 0, stream>>>(emb2c,nullptr,gWi,gbi,nullptr,nullptr,P3,MC_,384,128,0);
    const float* hin = (c4==0) ? hidden : Hc;
    float* hout = (c4==3) ? out_hidden : Hc;
    gru2_k<<<dim3(512), dim3(384), 0, stream>>>(P3,hin,dones,gWh,gbhn,P2,hout,c4*TC_,TC_);
  }

  // pack [W1|W2] for coupling
  pack_k<<<dim3(128), blk, 0, stream>>>(chw, bcat);

  for (int it=0; it<2; it++){
    // acat = e @ [W1|W2]  N=256
    gemm_k<0,false,false,false><<<dim3(4,512), blk, 0, stream>>>(P2,nullptr,bcat,nullptr,nullptr,nullptr,P3,M_,256,128,0);
    // coupling + context -> P0
    couple_k<<<dim3(T_*NE_), blk, 0, stream>>>(P3, P2, chb, cow, cob, P0);
    // dpre = relu(e@U1 + ctx@U2 + uhb)   dual-A K=256, split 128 -> P1
    gemm_k<1,true,false,false><<<dim3(2,512), blk, 0, stream>>>(P2,P0,uhw,uhb,nullptr,nullptr,P1,M_,128,256,128);
    // e = (e + relu(dpre@uow + uob)) * alive   (in place on P2)
    gemm_k<1,false,true,true><<<dim3(2,512), blk, 0, stream>>>(P1,nullptr,uow,uob,P2,dones,P2,M_,128,128,0);
  }
  // value head: v1 -> P3, v2 -> [P0;P1], values -> out
  gemm_k<1,false,false,false><<<dim3(4,512), blk, 0, stream>>>(P2,nullptr,v1w,v1b,nullptr,nullptr,P3,M_,256,128,0);
  gemm_k<1,false,false,false><<<dim3(4,512), blk, 0, stream>>>(P3,nullptr,v2w,v2b,nullptr,nullptr,v2,M_,256,256,0);
  vout_k<<<dim3(M_/4), blk, 0, stream>>>(v2, vow, vob, out_values);
}

// Round 4
// 773.742 us; speedup vs baseline: 2.0584x; 1.4526x over previous
//
#include <hip/hip_runtime.h>
#include <hip/hip_bf16.h>
#include <math.h>

#define T_ 128
#define NE_ 64
#define NA_ 8
#define B_ 512
#define OBS_ 64
#define D_ 128
#define CH_ 128
#define VH_ 256
#define M_ (T_*B_)   // 65536
#define TC_ 32       // GRU time-chunk
#define MC_ (TC_*B_) // 16384 rows per chunk

typedef __attribute__((ext_vector_type(8))) short bf16x8;   // 8 bf16 = 4 VGPRs
typedef __attribute__((ext_vector_type(4))) float f32x4;

__device__ __forceinline__ float sigmoidf_(float x){ return 1.f/(1.f+__expf(-x)); }

// ---------------------------------------------------------------------------
// fp32 tiled GEMM (pre-GRU path only): C[M,N] = epi(A[M,K] @ B[K,N] + bias)
// ---------------------------------------------------------------------------
template<int ACT>
__global__ __launch_bounds__(256)
void gemm_k(const float* __restrict__ A, const float* __restrict__ Bm,
            const float* __restrict__ bias, float* __restrict__ C,
            int M, int N, int K)
{
  constexpr int BM=128, BN=64, BK=16;
  __shared__ float As[BK][BM+4];
  __shared__ float Bs[BK][BN];
  const int tid = threadIdx.x;
  const int n0 = blockIdx.x * BN;
  const int m0 = blockIdx.y * BM;
  const int tn = tid & 15, tm = tid >> 4;

  float acc[8][4];
  #pragma unroll
  for (int r=0;r<8;r++)
    #pragma unroll
    for (int j=0;j<4;j++) acc[r][j]=0.f;

  for (int k0=0; k0<K; k0+=BK) {
    #pragma unroll
    for (int i=0;i<2;i++){
      int f = tid + i*256;
      int m = f >> 2, kq = (f & 3)*4;
      float4 v = *(const float4*)&A[(size_t)(m0+m)*K + k0 + kq];
      As[kq+0][m]=v.x; As[kq+1][m]=v.y; As[kq+2][m]=v.z; As[kq+3][m]=v.w;
    }
    {
      int f = tid;
      int k = f >> 4, nq = (f & 15)*4;
      *(float4*)&Bs[k][nq] = *(const float4*)&Bm[(size_t)(k0+k)*N + n0 + nq];
    }
    __syncthreads();
    #pragma unroll
    for (int k=0;k<BK;k++){
      float4 b4 = *(float4*)&Bs[k][tn*4];
      float4 a0 = *(float4*)&As[k][tm*8];
      float4 a1 = *(float4*)&As[k][tm*8+4];
      float av[8] = {a0.x,a0.y,a0.z,a0.w,a1.x,a1.y,a1.z,a1.w};
      float bv[4] = {b4.x,b4.y,b4.z,b4.w};
      #pragma unroll
      for (int r=0;r<8;r++)
        #pragma unroll
        for (int j=0;j<4;j++) acc[r][j] = fmaf(av[r], bv[j], acc[r][j]);
    }
    __syncthreads();
  }

  float4 bias4 = *(const float4*)&bias[n0 + tn*4];
  #pragma unroll
  for (int r=0;r<8;r++){
    int m = m0 + tm*8 + r;
    float4 c;
    c.x = acc[r][0]+bias4.x; c.y = acc[r][1]+bias4.y;
    c.z = acc[r][2]+bias4.z; c.w = acc[r][3]+bias4.w;
    if (ACT==1){ c.x=fmaxf(c.x,0.f); c.y=fmaxf(c.y,0.f); c.z=fmaxf(c.z,0.f); c.w=fmaxf(c.w,0.f); }
    *(float4*)&C[(size_t)m*N + n0 + tn*4] = c;
  }
}

// ---------------------------------------------------------------------------
// bf16 MFMA GEMM: C[M,N] = epi(A[M,K]_bf16 @ B[K,N]) with BT = B^T [N,K] bf16.
// 128x128 tile, BK=128 LDS chunks, 256 thr (2x2 waves of 64x64), 16x16x32 MFMA.
// DUAL: A split at k=128 into A(,:128) and A2(,:128) (both row-stride 128).
// Epilogue: +bias, ACT=relu, RESID(+fp32), SCALE(*alive), write fp32/bf16.
// ---------------------------------------------------------------------------
template<int ACT, bool DUAL, bool RESID, bool SCALE, bool WF32, bool WBF16>
__global__ __launch_bounds__(256)
void mgemm_k(const __hip_bfloat16* __restrict__ A, const __hip_bfloat16* __restrict__ A2,
             const __hip_bfloat16* __restrict__ BT, const float* __restrict__ bias,
             const float* __restrict__ resid, const int* __restrict__ dones,
             float* __restrict__ C, __hip_bfloat16* __restrict__ Cb,
             int M, int N, int K)
{
  __shared__ ushort As[128*136];   // [m][k], stride 136 breaks bank aliasing
  __shared__ ushort Bs[128*136];   // [n][k]
  const int tid  = threadIdx.x;
  const int lane = tid & 63, wave = tid >> 6;
  const int wm = wave >> 1, wn = wave & 1;
  const int quad = lane >> 4, ln = lane & 15;
  const int n0 = blockIdx.x * 128;
  const int m0 = blockIdx.y * 128;

  f32x4 acc[4][4];
  #pragma unroll
  for (int i=0;i<4;i++)
    #pragma unroll
    for (int j=0;j<4;j++)
      #pragma unroll
      for (int r=0;r<4;r++) acc[i][j][r] = 0.f;

  for (int kc=0; kc<K; kc+=128){
    const __hip_bfloat16* Ab; int arow, akoff;
    if (DUAL) { Ab = kc ? A2 : A; arow = 128; akoff = 0; }
    else      { Ab = A;           arow = K;   akoff = kc; }
    #pragma unroll
    for (int i=0;i<8;i++){                  // A tile: 2048 16B-chunks
      int c8 = tid + i*256;
      int m = c8 >> 4, kq = (c8 & 15)*8;
      *(uint4*)&As[m*136 + kq] = *(const uint4*)&Ab[(size_t)(m0+m)*arow + akoff + kq];
    }
    #pragma unroll
    for (int i=0;i<8;i++){                  // B tile from BT[N][K]
      int c8 = tid + i*256;
      int n = c8 >> 4, kq = (c8 & 15)*8;
      *(uint4*)&Bs[n*136 + kq] = *(const uint4*)&BT[(size_t)(n0+n)*K + kc + kq];
    }
    __syncthreads();
    #pragma unroll
    for (int ks=0; ks<4; ks++){             // 4 k-steps of 32
      const int kq = ks*32 + quad*8;
      bf16x8 af[4], bfv[4];
      #pragma unroll
      for (int mt=0;mt<4;mt++)
        af[mt] = *(const bf16x8*)&As[(wm*64 + mt*16 + ln)*136 + kq];
      #pragma unroll
      for (int nt=0;nt<4;nt++)
        bfv[nt] = *(const bf16x8*)&Bs[(wn*64 + nt*16 + ln)*136 + kq];
      #pragma unroll
      for (int mt=0;mt<4;mt++)
        #pragma unroll
        for (int nt=0;nt<4;nt++)
          acc[mt][nt] = __builtin_amdgcn_mfma_f32_16x16x32_bf16(af[mt], bfv[nt], acc[mt][nt], 0,0,0);
    }
    __syncthreads();
  }

  float biasv[4];
  #pragma unroll
  for (int nt=0;nt<4;nt++){
    int col = n0 + wn*64 + nt*16 + ln;
    biasv[nt] = bias ? bias[col] : 0.f;
  }
  #pragma unroll
  for (int mt=0;mt<4;mt++){
    #pragma unroll
    for (int r=0;r<4;r++){
      int row = m0 + wm*64 + mt*16 + quad*4 + r;
      float al = 1.f;
      if (SCALE) al = (dones[row]!=0) ? 0.f : 1.f;
      #pragma unroll
      for (int nt=0;nt<4;nt++){
        int col = n0 + wn*64 + nt*16 + ln;
        float v = acc[mt][nt][r] + biasv[nt];
        if (ACT==1) v = fmaxf(v, 0.f);
        if (RESID)  v += resid[(size_t)row*N + col];
        if (SCALE)  v *= al;
        if (WF32)   C[(size_t)row*N + col] = v;
        if (WBF16)  Cb[(size_t)row*N + col] = __float2bfloat16(v);
      }
    }
  }
}

// ---------------------------------------------------------------------------
// GRU scan, weights-in-registers (512 blocks x 384 thr, 1 row/block).
// Writes e (fp32) AND e_bf16, plus carried hidden.
// ---------------------------------------------------------------------------
__global__ __launch_bounds__(384)
void gru2_k(const float* __restrict__ gi, const float* __restrict__ hin,
            const int* __restrict__ dones, const float* __restrict__ Wh,
            const float* __restrict__ bhn, float* __restrict__ e_out,
            __hip_bfloat16* __restrict__ eb_out,
            float* __restrict__ hout, int t0, int tc)
{
  __shared__ float hs[D_];
  __shared__ float hsum[384];
  __shared__ float gis[384];
  __shared__ float dn[TC_];
  __shared__ float bhns[D_];
  const int row = blockIdx.x;
  const int c   = threadIdx.x;

  float w[D_];
  #pragma unroll
  for (int k=0;k<D_;k++) w[k] = Wh[(size_t)k*384 + c];

  for (int f=c; f<tc; f+=384)
    dn[f] = (dones[(size_t)(t0+f)*B_ + row] != 0) ? 1.f : 0.f;
  if (c < D_) { bhns[c] = bhn[c]; hs[c] = hin[(size_t)row*D_ + c]; }
  __syncthreads();
  if (c < D_ && dn[0] > 0.5f) hs[c] = 0.f;
  float gcur = gi[(size_t)row*384 + c];
  __syncthreads();

  for (int lt=0; lt<tc; lt++){
    float gn = 0.f;
    if (lt+1 < tc) gn = gi[((size_t)(lt+1)*B_ + row)*384 + c];
    float acc = 0.f;
    #pragma unroll
    for (int k4=0;k4<D_;k4+=4){
      float4 h4 = *(const float4*)&hs[k4];
      acc = fmaf(h4.x, w[k4+0], acc);
      acc = fmaf(h4.y, w[k4+1], acc);
      acc = fmaf(h4.z, w[k4+2], acc);
      acc = fmaf(h4.w, w[k4+3], acc);
    }
    hsum[c] = acc;
    gis[c]  = gcur;
    __syncthreads();
    if (c < D_){
      float rg = sigmoidf_(gis[c]     + hsum[c]);
      float zg = sigmoidf_(gis[c+128] + hsum[c+128]);
      float ng = tanhf(gis[c+256] + rg*(hsum[c+256] + bhns[c]));
      float hold = hs[c];
      float hnew = (1.f - zg)*ng + zg*hold;
      float ev = hnew * (1.f - dn[lt]);
      size_t eidx = ((size_t)(t0+lt)*B_ + row)*D_ + c;
      e_out[eidx]  = ev;
      eb_out[eidx] = __float2bfloat16(ev);
      float hv = hnew;
      if (lt+1 < tc && dn[lt+1] > 0.5f) hv = 0.f;
      hs[c] = hv;
    }
    __syncthreads();
    gcur = gn;
  }
  if (c < D_) hout[(size_t)row*D_ + c] = hs[c];
}

// ---------------------------------------------------------------------------
// Coupling per (t,env): C_ij = sigmoid(relu(ai+aj+cb).w + cob), C_ii=0;
// ctx[i] = sum_j C_ij e[j]   -> written as bf16.
// ---------------------------------------------------------------------------
__global__ __launch_bounds__(256)
void couple_k(const float* __restrict__ acat, const float* __restrict__ e,
              const float* __restrict__ chb, const float* __restrict__ cow,
              const float* __restrict__ cob, __hip_bfloat16* __restrict__ ctxb)
{
  __shared__ float ai[NA_][CH_], aj[NA_][CH_], es[NA_][D_], cbw[CH_], cww[CH_], Cs[NA_][NA_];
  const int m0 = blockIdx.x * NA_;
  const int tid = threadIdx.x;

  for (int f = tid; f < 512; f += 256) {
    int j = f >> 6, q = (f & 63)*4;
    float4 v = *(const float4*)&acat[(size_t)(m0+j)*256 + q];
    if (q < 128) *(float4*)&ai[j][q]     = v;
    else         *(float4*)&aj[j][q-128] = v;
  }
  {
    int f = tid;
    int j = f >> 5, q = (f & 31)*4;
    *(float4*)&es[j][q] = *(const float4*)&e[(size_t)(m0+j)*D_ + q];
  }
  if (tid < 128) { cbw[tid] = chb[tid]; cww[tid] = cow[tid]; }
  __syncthreads();

  {
    int p = tid >> 2, q = tid & 3;
    int i = p >> 3, j = p & 7;
    float s = 0.f;
    #pragma unroll
    for (int h = 0; h < 32; h++){
      int hh = q*32 + h;
      s += fmaxf(ai[i][hh] + aj[j][hh] + cbw[hh], 0.f) * cww[hh];
    }
    s += __shfl_down(s, 2);
    s += __shfl_down(s, 1);
    if (q == 0) {
      float Cv = sigmoidf_(s + cob[0]);
      Cs[i][j] = (i==j) ? 0.f : Cv;
    }
  }
  __syncthreads();
  #pragma unroll
  for (int rep=0; rep<4; rep++){
    int idx = rep*256 + tid;
    int i = idx >> 7, d = idx & 127;
    float s = 0.f;
    #pragma unroll
    for (int j=0;j<NA_;j++) s = fmaf(Cs[i][j], es[j][d], s);
    ctxb[(size_t)(m0+i)*D_ + d] = __float2bfloat16(s);
  }
}

// bcatT[n][k] (256x128 bf16): B[k][n] = n<128 ? chw[k][n] : chw[128+k][n-128]
__global__ __launch_bounds__(256)
void bcatT_k(const float* __restrict__ chw, __hip_bfloat16* __restrict__ dst)
{
  int idx = blockIdx.x*256 + threadIdx.x;    // 32768
  int n = idx >> 7, k = idx & 127;
  float v = (n < 128) ? chw[k*128 + n] : chw[(128+k)*128 + (n-128)];
  dst[idx] = __float2bfloat16(v);
}

// dst[c*R + r] = bf16(src[r*C + c]);  C = 1<<Cshift
__global__ __launch_bounds__(256)
void packT_k(const float* __restrict__ src, __hip_bfloat16* __restrict__ dst,
             int R, int Cshift)
{
  int idx = blockIdx.x*256 + threadIdx.x;
  int r = idx >> Cshift, c = idx & ((1<<Cshift)-1);
  dst[c*R + r] = __float2bfloat16(src[idx]);
}

// values[m] = v2[m] . w + b
__global__ __launch_bounds__(256)
void vout_k(const float* __restrict__ v2, const float* __restrict__ w,
            const float* __restrict__ b, float* __restrict__ values)
{
  int row  = blockIdx.x*4 + (threadIdx.x >> 6);
  int lane = threadIdx.x & 63;
  const float* vr = &v2[(size_t)row*VH_];
  float s = 0.f;
  #pragma unroll
  for (int i=0;i<4;i++) s = fmaf(vr[lane + 64*i], w[lane + 64*i], s);
  #pragma unroll
  for (int off=32; off; off>>=1) s += __shfl_down(s, off);
  if (lane==0) values[row] = s + b[0];
}

extern "C" void kernel_launch(void* const* d_in, const int* in_sizes, int n_in,
                              void* d_out, int out_size, void* d_ws, size_t ws_size,
                              hipStream_t stream) {
  const float* hidden = (const float*)d_in[0];
  const float* obs    = (const float*)d_in[1];
  const int*   dones  = (const int*)  d_in[2];
  const float* e1w = (const float*)d_in[3];
  const float* e1b = (const float*)d_in[4];
  const float* e2w = (const float*)d_in[5];
  const float* e2b = (const float*)d_in[6];
  const float* gWi = (const float*)d_in[7];
  const float* gbi = (const float*)d_in[8];
  const float* gWh = (const float*)d_in[9];
  const float* gbhn= (const float*)d_in[10];
  const float* chw = (const float*)d_in[11];
  const float* chb = (const float*)d_in[12];
  const float* cow = (const float*)d_in[13];
  const float* cob = (const float*)d_in[14];
  const float* uhw = (const float*)d_in[15];
  const float* uhb = (const float*)d_in[16];
  const float* uow = (const float*)d_in[17];
  const float* uob = (const float*)d_in[18];
  const float* v1w = (const float*)d_in[19];
  const float* v1b = (const float*)d_in[20];
  const float* v2w = (const float*)d_in[21];
  const float* v2b = (const float*)d_in[22];
  const float* vow = (const float*)d_in[23];
  const float* vob = (const float*)d_in[24];
  (void)in_sizes; (void)n_in; (void)out_size;

  float* out_hidden = (float*)d_out;
  float* out_values = (float*)d_out + (size_t)B_*D_;

  // Pools (float-slot offsets). Peak 54,681,600 floats = 218.7 MB.
  float* ws = (float*)d_ws;
  float* P0 = ws;                    //  8,388,608  emb1 / v1_bf16 (as bf16)
  float* P1 = ws + 8388608;          //  8,388,608  emb2
  float* P2 = ws + 16777216;         //  8,388,608  e fp32 (live whole session)
  float* P3 = ws + 25165824;         // 16,777,216  gi-chunk / acat fp32 / v2 fp32
  __hip_bfloat16* Xe  = (__hip_bfloat16*)(ws + 41943040);  // e bf16   (16MB)
  __hip_bfloat16* Xc  = (__hip_bfloat16*)(ws + 46137344);  // ctx bf16 (16MB)
  __hip_bfloat16* Xd  = (__hip_bfloat16*)(ws + 50331648);  // dpre bf16(16MB)
  float* Hc = ws + 54525952;         //     65,536  GRU hidden carry
  __hip_bfloat16* wT = (__hip_bfloat16*)(ws + 54591488);   // 180,224 bf16 weightsT
  __hip_bfloat16* v1b16 = (__hip_bfloat16*)P0;
  if (ws_size < (size_t)54681600 * sizeof(float)) return;

  __hip_bfloat16* bcatT = wT;            // [256][128]
  __hip_bfloat16* uhwT  = wT + 32768;    // [128][256]
  __hip_bfloat16* uowT  = wT + 65536;    // [128][128]
  __hip_bfloat16* v1wT  = wT + 81920;    // [256][128]
  __hip_bfloat16* v2wT  = wT + 114688;   // [256][256]

  dim3 blk(256);
  // pre-GRU path: exact fp32 (protects hidden-output threshold)
  gemm_k<1><<<dim3(2,512), blk, 0, stream>>>(obs,e1w,e1b,P0,M_,128,64);
  gemm_k<1><<<dim3(2,512), blk, 0, stream>>>(P0,e2w,e2b,P1,M_,128,128);

  for (int c4=0; c4<4; c4++){
    const float* emb2c = P1 + (size_t)c4*MC_*D_;
    gemm_k<0><<<dim3(6,128), blk, 0, stream>>>(emb2c,gWi,gbi,P3,MC_,384,128);
    const float* hin = (c4==0) ? hidden : Hc;
    float* hout = (c4==3) ? out_hidden : Hc;
    gru2_k<<<dim3(512), dim3(384), 0, stream>>>(P3,hin,dones,gWh,gbhn,P2,Xe,hout,c4*TC_,TC_);
  }

  // weight transposes to bf16 [N][K]
  bcatT_k<<<dim3(128), blk, 0, stream>>>(chw, bcatT);
  packT_k<<<dim3(128), blk, 0, stream>>>(uhw, uhwT, 256, 7);
  packT_k<<<dim3(64),  blk, 0, stream>>>(uow, uowT, 128, 7);
  packT_k<<<dim3(128), blk, 0, stream>>>(v1w, v1wT, 128, 8);
  packT_k<<<dim3(256), blk, 0, stream>>>(v2w, v2wT, 256, 8);

  for (int it=0; it<2; it++){
    // acat = e @ [W1|W2]  (fp32 out for couple_k)
    mgemm_k<0,false,false,false,true,false><<<dim3(2,512), blk, 0, stream>>>(
      Xe,nullptr,bcatT,nullptr,nullptr,nullptr,P3,nullptr,M_,256,128);
    // coupling + context -> ctx bf16
    couple_k<<<dim3(T_*NE_), blk, 0, stream>>>(P3, P2, chb, cow, cob, Xc);
    // dpre = relu([e|ctx] @ uhw + uhb) -> bf16
    mgemm_k<1,true,false,false,false,true><<<dim3(1,512), blk, 0, stream>>>(
      Xe,Xc,uhwT,uhb,nullptr,nullptr,nullptr,Xd,M_,128,256);
    // e = (e + relu(dpre @ uow + uob)) * alive  -> fp32 (in place) + bf16
    mgemm_k<1,false,true,true,true,true><<<dim3(1,512), blk, 0, stream>>>(
      Xd,nullptr,uowT,uob,P2,dones,P2,Xe,M_,128,128);
  }
  // value head
  mgemm_k<1,false,false,false,false,true><<<dim3(2,512), blk, 0, stream>>>(
    Xe,nullptr,v1wT,v1b,nullptr,nullptr,nullptr,v1b16,M_,256,128);
  mgemm_k<1,false,false,false,true,false><<<dim3(2,512), blk, 0, stream>>>(
    v1b16,nullptr,v2wT,v2b,nullptr,nullptr,P3,nullptr,M_,256,256);
  vout_k<<<dim3(M_/4), blk, 0, stream>>>(P3, vow, vob, out_values);
}